// Round 4
// baseline (67.346 us; speedup 1.0000x reference)
//
#include <hip/hip_runtime.h>

// Problem constants (from reference setup_inputs)
#define BATCH   32
#define CHANS   3
#define HW      4096      // 64*64, contiguous per (b,c) in NCHW fp32
#define NLEV    7
#define NEMBD   896
#define INNER   128       // 896 / 7
#define ROOTOFF 768       // (NLEV-1)*INNER
#define NCLS    1000

#define NRED    (BATCH * CHANS)      // 96 reducer blocks
#define NHEAD   ((NCLS + 15) / 16)   // 63 head blocks
#define MAGIC   0x1f2e3d4cu          // != 0xAAAAAAAA harness poison

// Exact collapse of the reference:
//   g[b,c]     = mean_{h,w} x[b,c,h,w]   (every tree level's hw-mean == g)
//   wfold[c,j] = sum_l emb_w[(l*3+c)*896 + 768+j]
//   out[b,k]   = d[k] + sum_c g[b,c]*M[c,k]
//     M[c,k]   = sum_j wfold[c,j]*cls_w[j*1000+k]   (batch-independent)
//     d[k]     = cls_b[k] + sum_j emb_b[768+j]*cls_w[j*1000+k]
// cls_w read exactly once (512 KB total).
//
// Single dispatch, 159 blocks: blocks 0..95 reduce x -> g (flag handshake),
// blocks 96..158 compute the head; their g-wait is hidden behind the cls_w
// streaming + LDS reduction. 159 < 256 CUs -> all blocks co-resident, no
// deadlock. Flags live in d_ws (re-poisoned to 0xAA each iter => reset).
__global__ __launch_bounds__(256) void k_fused(
        const float* __restrict__ x,
        const float* __restrict__ emb_w,
        const float* __restrict__ emb_b,
        const float* __restrict__ cls_w,
        const float* __restrict__ cls_b,
        float* __restrict__ out,
        float* __restrict__ g,                 // ws + 0   : 96 floats
        unsigned int* __restrict__ flags) {    // ws + 512 : 96 uints
    const int t = threadIdx.x;

    if (blockIdx.x < NRED) {
        // ---------------- reducer block: g[bc] = mean of x[b,c,:,:] --------
        const int bc = blockIdx.x;
        const float4* p4 = (const float4*)(x + (size_t)bc * HW);
        float s = 0.f;
#pragma unroll
        for (int i = 0; i < 4; ++i) {
            float4 v = p4[t + 256 * i];
            s += (v.x + v.y) + (v.z + v.w);
        }
#pragma unroll
        for (int off = 32; off > 0; off >>= 1)
            s += __shfl_down(s, off, 64);
        __shared__ float ls[4];
        if ((t & 63) == 0) ls[t >> 6] = s;
        __syncthreads();
        if (t == 0) {
            const float gv = (ls[0] + ls[1] + ls[2] + ls[3]) * (1.0f / HW);
            __hip_atomic_store(&g[bc], gv, __ATOMIC_RELAXED, __HIP_MEMORY_SCOPE_AGENT);
            __hip_atomic_store(&flags[bc], MAGIC, __ATOMIC_RELEASE, __HIP_MEMORY_SCOPE_AGENT);
        }
        return;
    }

    // ---------------- head block: 16 output columns ------------------------
    const int tx = t & 15;
    const int ty = t >> 4;
    const int k  = (blockIdx.x - NRED) * 16 + tx;
    const bool kok = (k < NCLS);

    __shared__ float wf0[INNER], wf1[INNER], wf2[INNER], eb[INNER];
    __shared__ float gsh[NRED];
    __shared__ float4 red[16][16];     // [ty][tx] partial (m0,m1,m2,d)
    __shared__ float4 fin[16];         // [tx] reduced

    // g-independent prep: folded weights + bias
    if (t < INNER) {
        float a0 = 0.f, a1 = 0.f, a2 = 0.f;
#pragma unroll
        for (int l = 0; l < NLEV; ++l) {
            const float* row = emb_w + (size_t)(l * CHANS) * NEMBD + ROOTOFF + t;
            a0 += row[0 * NEMBD];
            a1 += row[1 * NEMBD];
            a2 += row[2 * NEMBD];
        }
        wf0[t] = a0; wf1[t] = a1; wf2[t] = a2;
        eb[t]  = emb_b[ROOTOFF + t];
    }
    __syncthreads();

    // partial M/d over this thread's 8 j's (streams cls_w, one latency round)
    float m0 = 0.f, m1 = 0.f, m2 = 0.f, dd = 0.f;
    if (kok) {
        const int jb = ty * 8;
        float w[8];
#pragma unroll
        for (int jj = 0; jj < 8; ++jj)
            w[jj] = cls_w[(size_t)(jb + jj) * NCLS + k];
#pragma unroll
        for (int jj = 0; jj < 8; ++jj) {
            const int j = jb + jj;
            m0 += wf0[j] * w[jj];
            m1 += wf1[j] * w[jj];
            m2 += wf2[j] * w[jj];
            dd += eb[j]  * w[jj];
        }
    }
    red[ty][tx] = make_float4(m0, m1, m2, dd);

    // acquire g (reducers have been running this whole time)
    if (t < NRED) {
        while (__hip_atomic_load(&flags[t], __ATOMIC_ACQUIRE, __HIP_MEMORY_SCOPE_AGENT) != MAGIC) {}
        gsh[t] = __hip_atomic_load(&g[t], __ATOMIC_RELAXED, __HIP_MEMORY_SCOPE_AGENT);
    }
    __syncthreads();

    if (ty == 0) {
        float4 a = make_float4(0.f, 0.f, 0.f, kok ? cls_b[k] : 0.f);
#pragma unroll
        for (int yy = 0; yy < 16; ++yy) {
            float4 p = red[yy][tx];
            a.x += p.x; a.y += p.y; a.z += p.z; a.w += p.w;
        }
        fin[tx] = a;
    }
    __syncthreads();

    // fan-out: thread (tx,ty) writes batches b=ty and b=ty+16 for column k
    if (kok) {
        const float4 m = fin[tx];
#pragma unroll
        for (int h = 0; h < 2; ++h) {
            const int b = ty + 16 * h;
            const float* gb = gsh + b * CHANS;
            out[(size_t)b * NCLS + k] = m.w + gb[0] * m.x + gb[1] * m.y + gb[2] * m.z;
        }
    }
}

extern "C" void kernel_launch(void* const* d_in, const int* in_sizes, int n_in,
                              void* d_out, int out_size, void* d_ws, size_t ws_size,
                              hipStream_t stream) {
    const float* x     = (const float*)d_in[0];
    const float* emb_w = (const float*)d_in[1];
    const float* emb_b = (const float*)d_in[2];
    const float* cls_w = (const float*)d_in[3];
    const float* cls_b = (const float*)d_in[4];
    float* out = (float*)d_out;
    float* g   = (float*)d_ws;                                  // 96 floats
    unsigned int* flags = (unsigned int*)((char*)d_ws + 512);   // 96 uints

    k_fused<<<NRED + NHEAD, 256, 0, stream>>>(x, emb_w, emb_b, cls_w, cls_b,
                                              out, g, flags);
}

// Round 5
// 64.932 us; speedup vs baseline: 1.0372x; 1.0372x over previous
//
#include <hip/hip_runtime.h>

// Problem constants (from reference setup_inputs)
#define BATCH   32
#define CHANS   3
#define HW      4096      // 64*64, contiguous per (b,c) in NCHW fp32
#define NLEV    7
#define NEMBD   896
#define INNER   128       // 896 / 7
#define ROOTOFF 768       // (NLEV-1)*INNER
#define NCLS    1000

// Exact collapse of the reference:
//   g[b,c]     = mean_{h,w} x[b,c,h,w]   (every tree level's hw-mean == g)
//   wfold[c,j] = sum_l emb_w[(l*3+c)*896 + 768+j]
//   out[b,k]   = d[k] + sum_c g[b,c]*M[c,k]
//     M[c,k]   = sum_j wfold[c,j]*cls_w[j*1000+k]   (batch-independent)
//     d[k]     = cls_b[k] + sum_j emb_b[768+j]*cls_w[j*1000+k]
// cls_w read exactly once (512 KB total).
//
// R4 lesson: single-dispatch fusion with flag spin-wait REGRESSED (67.3 vs
// 64.9) — cross-XCD poll traffic costs more than a graph-replay launch gap.
// Keep the two-dispatch R3 structure; fix K2's load ordering instead (all
// independent global loads issued before the first barrier -> one HBM
// latency round instead of two).

// K1: per-(b,c) mean of x. 96 blocks x 256 threads, 16 floats/thread.
__global__ void k_reduce_x(const float* __restrict__ x, float* __restrict__ g) {
    const int bc = blockIdx.x;                    // 0..95
    const float4* p4 = (const float4*)(x + (size_t)bc * HW);
    const int t = threadIdx.x;
    float s = 0.f;
#pragma unroll
    for (int i = 0; i < 4; ++i) {
        float4 v = p4[t + 256 * i];
        s += (v.x + v.y) + (v.z + v.w);
    }
#pragma unroll
    for (int off = 32; off > 0; off >>= 1)
        s += __shfl_down(s, off, 64);
    __shared__ float ls[4];
    if ((t & 63) == 0) ls[t >> 6] = s;
    __syncthreads();
    if (t == 0)
        g[bc] = (ls[0] + ls[1] + ls[2] + ls[3]) * (1.0f / HW);
}

// K2: batch-factored head. grid = 63 blocks x 256 threads.
// ALL independent global loads (cls_w, g, cls_b, emb_w, emb_b) are issued
// before the first __syncthreads so they share one latency round.
__global__ __launch_bounds__(256) void k_head(
        const float* __restrict__ g,
        const float* __restrict__ emb_w,
        const float* __restrict__ emb_b,
        const float* __restrict__ cls_w,
        const float* __restrict__ cls_b,
        float* __restrict__ out) {
    const int t  = threadIdx.x;
    const int tx = t & 15;
    const int ty = t >> 4;
    const int k  = blockIdx.x * 16 + tx;
    const bool kok = (k < NCLS);

    __shared__ float wf0[INNER], wf1[INNER], wf2[INNER], eb[INNER];
    __shared__ float gsh[BATCH * CHANS];
    __shared__ float4 red[16][16];     // [ty][tx] partial (m0,m1,m2,d)
    __shared__ float4 fin[16];         // [tx] reduced

    // ---- issue ALL independent global loads up front ----
    float w[8];                        // this thread's cls_w strip
    const int jb = ty * 8;
    if (kok) {
#pragma unroll
        for (int jj = 0; jj < 8; ++jj)
            w[jj] = cls_w[(size_t)(jb + jj) * NCLS + k];
    }
    float cb = (ty == 0 && kok) ? cls_b[k] : 0.f;
    if (t < BATCH * CHANS) gsh[t] = g[t];

    if (t < INNER) {
        float a0 = 0.f, a1 = 0.f, a2 = 0.f;
#pragma unroll
        for (int l = 0; l < NLEV; ++l) {
            const float* row = emb_w + (size_t)(l * CHANS) * NEMBD + ROOTOFF + t;
            a0 += row[0 * NEMBD];
            a1 += row[1 * NEMBD];
            a2 += row[2 * NEMBD];
        }
        wf0[t] = a0; wf1[t] = a1; wf2[t] = a2;
        eb[t]  = emb_b[ROOTOFF + t];
    }
    __syncthreads();

    // ---- partial M/d over this thread's 8 j's (w[] already in regs) ----
    float m0 = 0.f, m1 = 0.f, m2 = 0.f, dd = 0.f;
    if (kok) {
#pragma unroll
        for (int jj = 0; jj < 8; ++jj) {
            const int j = jb + jj;
            m0 += wf0[j] * w[jj];
            m1 += wf1[j] * w[jj];
            m2 += wf2[j] * w[jj];
            dd += eb[j]  * w[jj];
        }
    }
    red[ty][tx] = make_float4(m0, m1, m2, dd);
    __syncthreads();

    if (ty == 0) {
        float4 a = make_float4(0.f, 0.f, 0.f, cb);
#pragma unroll
        for (int yy = 0; yy < 16; ++yy) {
            float4 p = red[yy][tx];
            a.x += p.x; a.y += p.y; a.z += p.z; a.w += p.w;
        }
        fin[tx] = a;
    }
    __syncthreads();

    // fan-out: thread (tx,ty) writes batches b=ty and b=ty+16 for column k
    if (kok) {
        const float4 m = fin[tx];
#pragma unroll
        for (int h = 0; h < 2; ++h) {
            const int b = ty + 16 * h;
            const float* gb = gsh + b * CHANS;
            out[(size_t)b * NCLS + k] = m.w + gb[0] * m.x + gb[1] * m.y + gb[2] * m.z;
        }
    }
}

extern "C" void kernel_launch(void* const* d_in, const int* in_sizes, int n_in,
                              void* d_out, int out_size, void* d_ws, size_t ws_size,
                              hipStream_t stream) {
    const float* x     = (const float*)d_in[0];
    const float* emb_w = (const float*)d_in[1];
    const float* emb_b = (const float*)d_in[2];
    const float* cls_w = (const float*)d_in[3];
    const float* cls_b = (const float*)d_in[4];
    float* out = (float*)d_out;
    float* g   = (float*)d_ws;   // 96 floats of scratch

    k_reduce_x<<<BATCH * CHANS, 256, 0, stream>>>(x, g);
    k_head<<<(NCLS + 15) / 16, 256, 0, stream>>>(g, emb_w, emb_b, cls_w, cls_b, out);
}